// Round 3
// baseline (33228.940 us; speedup 1.0000x reference)
//
#include <hip/hip_runtime.h>
#include <hip/hip_bf16.h>
#include <hip/hip_cooperative_groups.h>
#include <math.h>

namespace cg = cooperative_groups;

#define TT 512
#define BB 32
#define HH 1024
#define G4 4096   // 4*H

// persistent-kernel geometry
#define NBLK 256            // 1 block per CU
#define JPB 8               // hidden j per block (128 blocks/dir * 8 = 1024)
#define CHUNK 64            // k elements staged per chunk
#define NCHUNK (HH / CHUNK) // 16
#define WPAD 1028           // W row stride (floats): rows -> distinct bank groups
#define HPAD 76             // h row stride (floats): <=2-way on reads AND writes
#define WLDS_FLOATS (32 * WPAD)            // 32896
#define HLDS_FLOATS (2 * 32 * HPAD)        // 4864
#define LDS_BYTES ((WLDS_FLOATS + HLDS_FLOATS) * 4)  // 151,040 B < 160 KiB

__device__ __forceinline__ float sigmoidf_(float x) {
    return 1.0f / (1.0f + __expf(-x));
}
__device__ __forceinline__ float tanhf_(float x) {
    return 1.0f - 2.0f / (__expf(2.0f * x) + 1.0f);
}

// ---------------------------------------------------------------------------
// proj_kernel: Gx[d][t][b][r] = dot(x[b,t,:], W_ih_d[r,:]) + b_ih_d[r] + b_hh_d[r]
// GEMM M=T*B=16384 (m = t*32+b), N=4096, K=1024. Tile 128x128x32, 8x8/thread.
// ---------------------------------------------------------------------------
__global__ __launch_bounds__(256) void proj_kernel(
    const float* __restrict__ x,
    const float* __restrict__ Wih_f, const float* __restrict__ Wih_b,
    const float* __restrict__ bih_f, const float* __restrict__ bhh_f,
    const float* __restrict__ bih_b, const float* __restrict__ bhh_b,
    float* __restrict__ Gx)
{
    const int d = blockIdx.z;
    const float* __restrict__ W  = d ? Wih_b : Wih_f;
    const float* __restrict__ b1 = d ? bih_b : bih_f;
    const float* __restrict__ b2 = d ? bhh_b : bhh_f;
    const int r0 = blockIdx.x * 128;
    const int m0 = blockIdx.y * 128;

    __shared__ float As[128][36];
    __shared__ float Ws[128][36];

    const int tid = threadIdx.x;
    const int tx = tid & 15;
    const int ty = tid >> 4;

    float acc[8][8];
#pragma unroll
    for (int i = 0; i < 8; ++i)
#pragma unroll
        for (int j = 0; j < 8; ++j) acc[i][j] = 0.0f;

    const int lrow = tid >> 3;
    const int lk   = (tid & 7) * 4;

    for (int kc = 0; kc < 32; ++kc) {
        const int k0 = kc * 32;
#pragma unroll
        for (int l = 0; l < 4; ++l) {
            const int row = lrow + 32 * l;
            const int m = m0 + row;
            const int t = m >> 5, b = m & 31;
            *(float4*)&As[row][lk] =
                *(const float4*)(x + ((size_t)b * TT + t) * HH + k0 + lk);
            *(float4*)&Ws[row][lk] =
                *(const float4*)(W + (size_t)(r0 + row) * HH + k0 + lk);
        }
        __syncthreads();
#pragma unroll
        for (int k = 0; k < 32; k += 4) {
            float4 a[8], w[8];
#pragma unroll
            for (int mi = 0; mi < 8; ++mi) a[mi] = *(const float4*)&As[ty + 16 * mi][k];
#pragma unroll
            for (int ci = 0; ci < 8; ++ci) w[ci] = *(const float4*)&Ws[tx + 16 * ci][k];
#pragma unroll
            for (int mi = 0; mi < 8; ++mi)
#pragma unroll
                for (int ci = 0; ci < 8; ++ci)
                    acc[mi][ci] += a[mi].x * w[ci].x + a[mi].y * w[ci].y +
                                   a[mi].z * w[ci].z + a[mi].w * w[ci].w;
        }
        __syncthreads();
    }

#pragma unroll
    for (int mi = 0; mi < 8; ++mi) {
        const int m = m0 + ty + 16 * mi;
#pragma unroll
        for (int ci = 0; ci < 8; ++ci) {
            const int r = r0 + tx + 16 * ci;
            Gx[((size_t)d * TT * BB + m) * (size_t)G4 + r] =
                acc[mi][ci] + b1[r] + b2[r];
        }
    }
}

// ---------------------------------------------------------------------------
// lstm_persist: the entire recurrence, both directions, in ONE cooperative
// kernel. 256 blocks (1/CU): block = dir d (bid>>7) x 8 hidden-j (bid&127).
// W_hh slice (32 gate rows x 1024) resident in LDS for all 512 steps.
// Thread mapping: c = tid&7 (j), kk = (tid>>3)&1 (k-half), rb = tid>>4
// (batch pair 2rb, 2rb+1). Each thread: acc[2 batches][4 gates] over its
// k-half; partner-reduce via __shfl_xor(.,8); lane keeps batch b = 2rb+kk.
// c-state lives in a register across all steps. One grid.sync per step.
// ---------------------------------------------------------------------------
__global__ __launch_bounds__(256, 1) void lstm_persist(
    const float* __restrict__ Gx,
    const float* __restrict__ Whh_f, const float* __restrict__ Whh_b,
    float* __restrict__ hs_fw, float* __restrict__ hs_bw)
{
    extern __shared__ float lds[];
    float* __restrict__ Wlds = lds;                    // [32][WPAD]
    float* __restrict__ HsB  = lds + WLDS_FLOATS;      // [2][32][HPAD]

    const int bid = blockIdx.x;
    const int d   = bid >> 7;
    const int j0  = (bid & 127) * JPB;
    const float* __restrict__ Whh = d ? Whh_b : Whh_f;
    float* __restrict__ hs = d ? hs_bw : hs_fw;

    const int tid = threadIdx.x;
    const int c   = tid & 7;
    const int kk  = (tid >> 3) & 1;
    const int rb  = tid >> 4;
    const int kk4 = kk * 4;

    // ---- load W slice into LDS once (row lr = gate*8 + jj) ----
    {
        const int lr = tid >> 3;               // 0..31
        const int g = lr >> 3, jj = lr & 7;
        const float* src = Whh + ((size_t)g * HH + j0 + jj) * HH;
        float* dst = Wlds + (size_t)lr * WPAD;
        const int col0 = (tid & 7) * 4;
#pragma unroll
        for (int i = 0; i < 32; ++i)
            *(float4*)(dst + col0 + i * 32) = *(const float4*)(src + col0 + i * 32);
    }
    __syncthreads();

    cg::grid_group grid = cg::this_grid();

    const int b = 2 * rb + kk;        // this lane's final batch
    const int j = j0 + c;
    const int srow = tid >> 3;        // staging row (batch 0..31)
    const int scol = (tid & 7) * 8;   // staging col (2 float4)
    const float* __restrict__ wcol0 = Wlds + (size_t)c * WPAD;

    float cst = 0.0f;

    for (int s = 0; s < TT; ++s) {
        const int t = d ? (TT - 1 - s) : s;

        // Gx prefetch (latency hides under the matmul below)
        const float* gxp = Gx + (((size_t)d * TT + t) * BB + b) * (size_t)G4 + j;
        const float gx0 = gxp[0 * HH];
        const float gx1 = gxp[1 * HH];
        const float gx2 = gxp[2 * HH];
        const float gx3 = gxp[3 * HH];

        float acc[2][4];
#pragma unroll
        for (int bi = 0; bi < 2; ++bi)
#pragma unroll
            for (int ri = 0; ri < 4; ++ri) acc[bi][ri] = 0.0f;

        if (s > 0) {  // h_prev == 0 at s==0
            const float* __restrict__ hp =
                hs + (size_t)(d ? (t + 1) : (t - 1)) * BB * HH;
            const float* hsrc = hp + (size_t)srow * HH + scol;
            float4 pf0 = *(const float4*)(hsrc);
            float4 pf1 = *(const float4*)(hsrc + 4);

            for (int kc = 0; kc < NCHUNK; ++kc) {
                float* __restrict__ buf = HsB + (kc & 1) * 32 * HPAD;
                *(float4*)(buf + srow * HPAD + scol)     = pf0;
                *(float4*)(buf + srow * HPAD + scol + 4) = pf1;
                if (kc + 1 < NCHUNK) {  // in flight across barrier+compute
                    pf0 = *(const float4*)(hsrc + (kc + 1) * CHUNK);
                    pf1 = *(const float4*)(hsrc + (kc + 1) * CHUNK + 4);
                }
                __syncthreads();
                const float* __restrict__ hb0 = buf + (2 * rb) * HPAD;
                const float* __restrict__ hb1 = buf + (2 * rb + 1) * HPAD;
                const float* __restrict__ wp0 = wcol0 + kc * CHUNK;
#pragma unroll
                for (int kq = 0; kq < 8; ++kq) {
                    const int ko = kq * 8 + kk4;
                    const float4 h0 = *(const float4*)(hb0 + ko);
                    const float4 h1 = *(const float4*)(hb1 + ko);
#pragma unroll
                    for (int ri = 0; ri < 4; ++ri) {
                        const float4 w = *(const float4*)(wp0 + ri * 8 * WPAD + ko);
                        acc[0][ri] += h0.x * w.x + h0.y * w.y + h0.z * w.z + h0.w * w.w;
                        acc[1][ri] += h1.x * w.x + h1.y * w.y + h1.z * w.z + h1.w * w.w;
                    }
                }
                // next iter writes the OTHER buffer; the write that re-targets
                // THIS buffer (kc+2) is fenced by barrier(kc+1). Single-barrier
                // double-buffer rotation is hazard-free.
            }
        }

        // ---- reduce the k-split (partner lane tid^8 holds the other half)
#pragma unroll
        for (int bi = 0; bi < 2; ++bi)
#pragma unroll
            for (int ri = 0; ri < 4; ++ri)
                acc[bi][ri] += __shfl_xor(acc[bi][ri], 8, 64);

        // lane keeps batch bi == kk (compile-time-indexed acc, cndmask select)
        const float p0 = (kk ? acc[1][0] : acc[0][0]) + gx0;
        const float p1 = (kk ? acc[1][1] : acc[0][1]) + gx1;
        const float p2 = (kk ? acc[1][2] : acc[0][2]) + gx2;
        const float p3 = (kk ? acc[1][3] : acc[0][3]) + gx3;

        const float gi = sigmoidf_(p0);
        const float gf = sigmoidf_(p1);
        const float gg = tanhf_(p2);
        const float go = sigmoidf_(p3);
        cst = gf * cst + gi * gg;
        hs[((size_t)t * BB + b) * HH + j] = go * tanhf_(cst);

        __threadfence();
        grid.sync();
    }
}

// ---------------------------------------------------------------------------
// step_kernel: FALLBACK path (one launch per timestep) if cooperative launch
// is unavailable. Identical math; also handles the no-Gx (small ws) case.
// ---------------------------------------------------------------------------
__global__ __launch_bounds__(256) void step_kernel(
    const float* __restrict__ x, const float* __restrict__ Gx,
    const float* __restrict__ Whh_f, const float* __restrict__ Whh_b,
    const float* __restrict__ Wih_f, const float* __restrict__ Wih_b,
    const float* __restrict__ bih_f, const float* __restrict__ bhh_f,
    const float* __restrict__ bih_b, const float* __restrict__ bhh_b,
    float* __restrict__ hs_fw, float* __restrict__ hs_bw,
    float* __restrict__ c_f, float* __restrict__ c_b,
    int s, int use_gx)
{
    const int d = blockIdx.y;
    const int t = d ? (TT - 1 - s) : s;
    const float* __restrict__ Whh = d ? Whh_b : Whh_f;
    const float* __restrict__ Wih = d ? Wih_b : Wih_f;
    float* __restrict__ hs  = d ? hs_bw : hs_fw;
    float* __restrict__ cst = d ? c_b : c_f;
    const float* hprev = (s > 0)
        ? hs + (size_t)((d ? (t + 1) : (t - 1)) * BB) * HH : nullptr;

    const int j0 = blockIdx.x * 8;

    __shared__ float Hs[2][32][36];
    __shared__ float Ws[2][32][36];

    const int tid  = threadIdx.x;
    const int c    = tid & 7;
    const int rb   = tid >> 3;
    const int srow = tid >> 3;
    const int lk   = (tid & 7) * 4;

    float acc[4] = {0.f, 0.f, 0.f, 0.f};

    for (int part = 0; part < 2; ++part) {
        if (part == 0 && use_gx) continue;
        if (part == 1 && s == 0) break;
        const float* __restrict__ Wmat = (part == 0) ? Wih : Whh;
        const int g = srow >> 3, jj = srow & 7;
        const float* __restrict__ wsrc =
            Wmat + ((size_t)g * HH + j0 + jj) * HH + lk;
        const float* __restrict__ hsrc = (part == 0)
            ? x + ((size_t)srow * TT + t) * HH + lk
            : hprev + (size_t)srow * HH + lk;

        float4 hreg = *(const float4*)(hsrc);
        float4 wreg = *(const float4*)(wsrc);

        for (int kc = 0; kc < 32; ++kc) {
            const int cur = kc & 1;
            *(float4*)&Hs[cur][srow][lk] = hreg;
            *(float4*)&Ws[cur][srow][lk] = wreg;
            if (kc < 31) {
                hreg = *(const float4*)(hsrc + (kc + 1) * 32);
                wreg = *(const float4*)(wsrc + (kc + 1) * 32);
            }
            __syncthreads();
#pragma unroll
            for (int k = 0; k < 32; k += 4) {
                const float4 h = *(const float4*)&Hs[cur][rb][k];
#pragma unroll
                for (int ri = 0; ri < 4; ++ri) {
                    const float4 w = *(const float4*)&Ws[cur][ri * 8 + c][k];
                    acc[ri] += h.x * w.x + h.y * w.y + h.z * w.z + h.w * w.w;
                }
            }
        }
        __syncthreads();
    }

    const int j = j0 + c;
    const int b = rb;
    const float* __restrict__ bih = d ? bih_b : bih_f;
    const float* __restrict__ bhh = d ? bhh_b : bhh_f;
    float pre[4];
#pragma unroll
    for (int ri = 0; ri < 4; ++ri) {
        float add;
        if (use_gx)
            add = Gx[(((size_t)d * TT + t) * BB + b) * (size_t)G4 +
                     (size_t)ri * HH + j];
        else
            add = bih[ri * HH + j] + bhh[ri * HH + j];
        pre[ri] = acc[ri] + add;
    }
    const float gi = sigmoidf_(pre[0]);
    const float gf = sigmoidf_(pre[1]);
    const float gg = tanhf_(pre[2]);
    const float go = sigmoidf_(pre[3]);
    const size_t cidx = (size_t)b * HH + j;
    const float cprev = (s > 0) ? cst[cidx] : 0.0f;
    const float cn = gf * cprev + gi * gg;
    cst[cidx] = cn;
    hs[((size_t)t * BB + b) * HH + j] = go * tanhf_(cn);
}

// ---------------------------------------------------------------------------
// gate_kernel: sigma = sigmoid([fw,bw] @ Wg^T + bg); out = sigma*fw+(1-sigma)*bw
// ---------------------------------------------------------------------------
__global__ __launch_bounds__(256) void gate_kernel(
    const float* __restrict__ hs_fw, const float* __restrict__ hs_bw,
    const float* __restrict__ Wg, const float* __restrict__ bg,
    float* __restrict__ out)
{
    const int j0 = blockIdx.x * 128;
    const int m0 = blockIdx.y * 128;

    __shared__ float As[128][36];
    __shared__ float Ws[128][36];

    const int tid = threadIdx.x;
    const int tx = tid & 15;
    const int ty = tid >> 4;

    float acc[8][8];
#pragma unroll
    for (int i = 0; i < 8; ++i)
#pragma unroll
        for (int j = 0; j < 8; ++j) acc[i][j] = 0.0f;

    const int lrow = tid >> 3;
    const int lk   = (tid & 7) * 4;

    for (int kc = 0; kc < 64; ++kc) {
        const int k0 = kc * 32;
        const float* __restrict__ A = (k0 < HH) ? hs_fw : hs_bw;
        const int ka = k0 & (HH - 1);
#pragma unroll
        for (int l = 0; l < 4; ++l) {
            const int row = lrow + 32 * l;
            *(float4*)&As[row][lk] =
                *(const float4*)(A + (size_t)(m0 + row) * HH + ka + lk);
            *(float4*)&Ws[row][lk] =
                *(const float4*)(Wg + (size_t)(j0 + row) * (2 * HH) + k0 + lk);
        }
        __syncthreads();
#pragma unroll
        for (int k = 0; k < 32; k += 4) {
            float4 a[8], w[8];
#pragma unroll
            for (int mi = 0; mi < 8; ++mi) a[mi] = *(const float4*)&As[ty + 16 * mi][k];
#pragma unroll
            for (int ci = 0; ci < 8; ++ci) w[ci] = *(const float4*)&Ws[tx + 16 * ci][k];
#pragma unroll
            for (int mi = 0; mi < 8; ++mi)
#pragma unroll
                for (int ci = 0; ci < 8; ++ci)
                    acc[mi][ci] += a[mi].x * w[ci].x + a[mi].y * w[ci].y +
                                   a[mi].z * w[ci].z + a[mi].w * w[ci].w;
        }
        __syncthreads();
    }

#pragma unroll
    for (int mi = 0; mi < 8; ++mi) {
        const int m = m0 + ty + 16 * mi;
        const int b = m & 31, t = m >> 5;
#pragma unroll
        for (int ci = 0; ci < 8; ++ci) {
            const int j = j0 + tx + 16 * ci;
            const float sg = sigmoidf_(acc[mi][ci] + bg[j]);
            const float fw = hs_fw[(size_t)m * HH + j];
            const float bw = hs_bw[(size_t)m * HH + j];
            out[((size_t)b * TT + t) * HH + j] = sg * fw + (1.0f - sg) * bw;
        }
    }
}

// ---------------------------------------------------------------------------
extern "C" void kernel_launch(void* const* d_in, const int* in_sizes, int n_in,
                              void* d_out, int out_size, void* d_ws, size_t ws_size,
                              hipStream_t stream)
{
    const float* x     = (const float*)d_in[0];
    const float* Wih_f = (const float*)d_in[1];
    const float* Whh_f = (const float*)d_in[2];
    const float* bih_f = (const float*)d_in[3];
    const float* bhh_f = (const float*)d_in[4];
    const float* Wih_b = (const float*)d_in[5];
    const float* Whh_b = (const float*)d_in[6];
    const float* bih_b = (const float*)d_in[7];
    const float* bhh_b = (const float*)d_in[8];
    const float* Wg    = (const float*)d_in[9];
    const float* bg    = (const float*)d_in[10];
    float* out = (float*)d_out;

    float* ws = (float*)d_ws;
    const size_t nhs = (size_t)TT * BB * HH;
    float* hs_fw = ws;
    float* hs_bw = hs_fw + nhs;
    float* c_f   = hs_bw + nhs;
    float* c_b   = c_f + (size_t)BB * HH;
    float* Gx    = c_b + (size_t)BB * HH;
    const size_t need_gx =
        (2 * nhs + 2 * (size_t)BB * HH + (size_t)2 * TT * BB * G4) * sizeof(float);
    const int use_gx = (ws_size >= need_gx) ? 1 : 0;

    if (use_gx) {
        proj_kernel<<<dim3(G4 / 128, (TT * BB) / 128, 2), 256, 0, stream>>>(
            x, Wih_f, Wih_b, bih_f, bhh_f, bih_b, bhh_b, Gx);
    }

    // deterministic capability gate for the cooperative persistent path
    int dev = 0, coop = 0;
    hipGetDevice(&dev);
    hipDeviceGetAttribute(&coop, hipDeviceAttributeCooperativeLaunch, dev);

    bool did_persist = false;
    if (use_gx && coop) {
        (void)hipFuncSetAttribute((const void*)lstm_persist,
                                  hipFuncAttributeMaxDynamicSharedMemorySize,
                                  LDS_BYTES);
        const float* Gx_c = Gx;
        void* kargs[] = {(void*)&Gx_c, (void*)&Whh_f, (void*)&Whh_b,
                         (void*)&hs_fw, (void*)&hs_bw};
        hipError_t e = hipLaunchCooperativeKernel(
            (const void*)lstm_persist, dim3(NBLK), dim3(256), kargs,
            (unsigned int)LDS_BYTES, stream);
        did_persist = (e == hipSuccess);
    }
    if (!did_persist) {
        for (int s = 0; s < TT; ++s) {
            step_kernel<<<dim3(HH / 8, 2), 256, 0, stream>>>(
                x, Gx, Whh_f, Whh_b, Wih_f, Wih_b,
                bih_f, bhh_f, bih_b, bhh_b,
                hs_fw, hs_bw, c_f, c_b, s, use_gx);
        }
    }

    gate_kernel<<<dim3(HH / 128, (TT * BB) / 128), 256, 0, stream>>>(
        hs_fw, hs_bw, Wg, bg, out);
}